// Round 1
// 880.379 us; speedup vs baseline: 1.0518x; 1.0518x over previous
//
#include <hip/hip_runtime.h>
#include <math.h>

#define BB 2
#define LL 1024
#define DD 768
#define DI 1536
#define NS 16
#define DRR 48
#define KC 4
#define VOC 32000
#define BT (BB*LL)          // 2048 rows
#define EPS 1e-5f

#define NCH 16              // scan chunks
#define TC  (LL/NCH)        // 64 timesteps per chunk
#define CHW ((DI/16)*256)   // elems per (b,chunk) in state bufs = 24576

typedef __attribute__((ext_vector_type(4))) float f32x4;
typedef __attribute__((ext_vector_type(8))) short short8;
typedef unsigned short ushort_t;

__device__ __forceinline__ unsigned short f2bf(float f) {
    unsigned int u = __float_as_uint(f);
    u += 0x7FFFu + ((u >> 16) & 1u);   // RNE
    return (unsigned short)(u >> 16);
}

// async global->LDS, 16B per lane; lds base must be wave-uniform, HW adds lane*16
#define GLDS(gp, lp) __builtin_amdgcn_global_load_lds( \
    (const __attribute__((address_space(1))) unsigned int*)(gp), \
    (__attribute__((address_space(3))) unsigned int*)(lp), 16, 0, 0)

// 16-lane (DPP row) sum reduction, all VALU-rate: quad_perm swaps + mirrors
#define DPP_ADD(c, ctrl) ((c) + __int_as_float(__builtin_amdgcn_update_dpp( \
    0, __float_as_int(c), (ctrl), 0xF, 0xF, true)))

// ---------------------------------------------------------------------------
// C = A(MxK,bf16) * W(NxK,bf16)^T [+C / atomic], fp32 out.
// m97 structure: 128x128 tile, BK=32, global_load_lds width-16 staging.
// Used for the small/medium GEMMs (in_proj, bcd, out_proj).
// ---------------------------------------------------------------------------
template<bool ADD, bool NMASK, bool ATOMIC>
__global__ __launch_bounds__(256) void gemm_bf16(
    const ushort_t* __restrict__ A, const ushort_t* __restrict__ W,
    float* C, int Nn, int lda, int ldc, int kchunk)
{
    __shared__ __align__(16) ushort_t As[128 * 32];
    __shared__ __align__(16) ushort_t Ws[128 * 32];

    const int row0 = blockIdx.x * 128;
    const int col0 = blockIdx.y * 128;
    const int tid  = threadIdx.x;
    const int lane = tid & 63;
    const int wave = tid >> 6;
    const int wm   = (wave & 1) * 64;
    const int wn   = (wave >> 1) * 64;
    const int mrow = lane & 15;
    const int quad = lane >> 4;

    const int kb = blockIdx.z * kchunk;

    const int srow = tid >> 2;
    const int scol = (tid & 3) << 3;
    const ushort_t* gA0 = A + (size_t)(row0 + srow) * lda + scol;
    const ushort_t* gA1 = A + (size_t)(row0 + 64 + srow) * lda + scol;
    const ushort_t* gW0 = W + (size_t)(col0 + srow) * lda + scol;
    const ushort_t* gW1 = W + (size_t)(col0 + 64 + srow) * lda + scol;
    char* lA0 = (char*)As + wave * 1024;
    char* lA1 = (char*)As + 4096 + wave * 1024;
    char* lW0 = (char*)Ws + wave * 1024;
    char* lW1 = (char*)Ws + 4096 + wave * 1024;

    f32x4 acc[4][4];
#pragma unroll
    for (int i = 0; i < 4; ++i)
#pragma unroll
        for (int j = 0; j < 4; ++j)
            acc[i][j] = (f32x4){0.f, 0.f, 0.f, 0.f};

    for (int k0 = kb; k0 < kb + kchunk; k0 += 32) {
        GLDS(gA0 + k0, lA0);
        GLDS(gA1 + k0, lA1);
        GLDS(gW0 + k0, lW0);
        GLDS(gW1 + k0, lW1);
        __syncthreads();

        short8 af[4], wf[4];
#pragma unroll
        for (int i = 0; i < 4; ++i) {
            af[i] = *(const short8*)&As[(wm + i * 16 + mrow) * 32 + quad * 8];
            wf[i] = *(const short8*)&Ws[(wn + i * 16 + mrow) * 32 + quad * 8];
        }
#pragma unroll
        for (int i = 0; i < 4; ++i)
#pragma unroll
            for (int j = 0; j < 4; ++j)
                acc[i][j] = __builtin_amdgcn_mfma_f32_16x16x32_bf16(
                    af[i], wf[j], acc[i][j], 0, 0, 0);
        __syncthreads();
    }

#pragma unroll
    for (int i = 0; i < 4; ++i)
#pragma unroll
        for (int j = 0; j < 4; ++j)
#pragma unroll
            for (int r = 0; r < 4; ++r) {
                int row = row0 + wm + i * 16 + quad * 4 + r;
                int col = col0 + wn + j * 16 + mrow;
                if (!NMASK || col < Nn) {
                    float v = acc[i][j][r];
                    size_t off = (size_t)row * ldc + col;
                    if (ATOMIC) {
                        atomicAdd(&C[off], v);
                    } else {
                        if (ADD) v += C[off];
                        C[off] = v;
                    }
                }
            }
}

// ---------------------------------------------------------------------------
// 256x256 deep-pipelined logits GEMM: C(2048x32000,f32) = A(2048x768) W(32000x768)^T
// T1 XCD swizzle + T2 LDS XOR swizzle + T3 phase-split + T4 counted vmcnt + T5 setprio.
//
// Geometry: BM=BN=256, BK=64 split as 2 K-halves of 32. 8 waves (2M x 4N),
// per-wave output 128x64 (acc[8][4] f32x4). LDS = 8 slots x 16KB = 128KB:
// slot(j) = j&7 where unit stream j = 4t + 2h + e  (t=K-tile, h=K-half,
// e=0:A[256x32], e=1:B[256x32]).  Per K-tile: 4 phases of 16 MFMA each
// (phase p = 2h+m2; m2 selects M-frag group 0-3 / 4-7). Each phase stages one
// unit at prefetch offset +6 (2 x global_load_lds w16, source pre-swizzled,
// LDS dest linear, reads swizzled: rule #21).  s_waitcnt vmcnt(8) once per
// K-half (end of odd phases), draining 8->4->0 only in the final two tiles.
// Slot-reuse safety: unit j issued at phase j-6; previous occupant j-8 fully
// read by phase j-7 (>=1 barrier before issue). Landing safety: pair (g,g+1)
// first read at phase g; wait at end of phase g-1 leaves <=4 units (8 loads)
// outstanding => units <= g+1 landed for every wave, barrier publishes.
//
// LDS swizzle: row stride 64B; byte ^= ((byte>>7)&3)<<4 spreads 8 consecutive
// rows over 8 distinct 16B slots (16-lane ds_read_b128 -> 2-way max = free).
// Involution (bits 4-5 keyed off bits 7-8) so stage-source uses same XOR.
// ---------------------------------------------------------------------------
#define GK  768
#define GN  32000
#define NT12 12

__device__ __forceinline__ void stage_unit(
    int j, char* ldsw, const char* sA0, const char* sA1,
    const char* sB0, const char* sB1)
{
    if (j >= 4 * NT12) return;
    int tt = j >> 2, hh = (j >> 1) & 1, ee = j & 1;
    int koff = tt * 128 + hh * 64;           // bytes into the K dimension
    char* dst = ldsw + (j & 7) * 16384;
    const char* s0 = (ee ? sB0 : sA0) + koff;
    const char* s1 = (ee ? sB1 : sA1) + koff;
    GLDS(s0, dst);
    GLDS(s1, dst + 8192);
}

#define VMCNT(N) asm volatile("s_waitcnt vmcnt(" #N ")" ::: "memory")

#define SBAR() do { __builtin_amdgcn_sched_barrier(0); \
    __builtin_amdgcn_s_barrier(); \
    __builtin_amdgcn_sched_barrier(0); } while (0)

#define MFMA16(M2) do { \
    __builtin_amdgcn_s_setprio(1); \
    _Pragma("unroll") \
    for (int i_ = 0; i_ < 4; ++i_) \
        _Pragma("unroll") \
        for (int n_ = 0; n_ < 4; ++n_) \
            acc[(M2)*4 + i_][n_] = __builtin_amdgcn_mfma_f32_16x16x32_bf16( \
                af[i_], wf[n_], acc[(M2)*4 + i_][n_], 0, 0, 0); \
    __builtin_amdgcn_s_setprio(0); \
} while (0)

#define PHASE(T, H, M2, LOADB, WAITSTMT) do { \
    const char* bufA_ = ldsc + ((T) & 1) * 65536 + (H) * 32768; \
    if (LOADB) { \
        _Pragma("unroll") \
        for (int n_ = 0; n_ < 4; ++n_) \
            wf[n_] = *(const short8*)(bufA_ + 16384 + offB[n_]); \
    } \
    _Pragma("unroll") \
    for (int i_ = 0; i_ < 4; ++i_) \
        af[i_] = *(const short8*)(bufA_ + offA[(M2)*4 + i_]); \
    stage_unit(4*(T) + 2*(H) + (M2) + 6, ldsw, sA0, sA1, sB0, sB1); \
    SBAR(); \
    MFMA16(M2); \
    WAITSTMT; \
    SBAR(); \
} while (0)

#define TILE(T, W1, W2) do { \
    PHASE(T, 0, 0, true,  (void)0); \
    PHASE(T, 0, 1, false, W1); \
    PHASE(T, 1, 0, true,  (void)0); \
    PHASE(T, 1, 1, false, W2); \
} while (0)

__global__ __launch_bounds__(512, 2) void gemm_logits_256(
    const ushort_t* __restrict__ A, const ushort_t* __restrict__ W,
    float* __restrict__ C)
{
    __shared__ __align__(16) char ldsc[131072];

    // T1: bijective XCD swizzle (1000 % 8 == 0); each XCD owns contiguous
    // s-range -> all 8 m-tiles of a B-panel land on the same L2.
    const int bid = blockIdx.x;
    const int s   = (bid & 7) * 125 + (bid >> 3);
    const int mt  = s & 7;        // M tile (8)
    const int nt  = s >> 3;       // N tile (125)

    const int tid  = threadIdx.x;
    const int lane = tid & 63;
    const int wave = tid >> 6;
    const int wm   = wave >> 2;   // 0..1
    const int wn   = wave & 3;    // 0..3
    const int mrow = lane & 15;
    const int quad = lane >> 4;

    // swizzled ds_read byte offsets within a 256x32 (16KB) unit
    int offA[8], offB[4];
#pragma unroll
    for (int m = 0; m < 8; ++m) {
        int r = wm * 128 + m * 16 + mrow;
        offA[m] = r * 64 + ((quad * 16) ^ (((r >> 1) & 3) << 4));
    }
#pragma unroll
    for (int n = 0; n < 4; ++n) {
        int r = wn * 64 + n * 16 + mrow;
        offB[n] = r * 64 + ((quad * 16) ^ (((r >> 1) & 3) << 4));
    }

    // staging: thread covers LDS chunks X0=tid*16 (rows 0-127) and X0+8192
    // (rows 128-255); global source pre-swizzled with the same involution.
    const int X0 = tid * 16;
    const int L0 = X0 ^ (((X0 >> 7) & 3) << 4);
    const int r0 = L0 >> 6, c0 = L0 & 63;
    const char* sA0 = (const char*)A + ((size_t)(mt * 256 +       r0) * GK) * 2 + c0;
    const char* sA1 = (const char*)A + ((size_t)(mt * 256 + 128 + r0) * GK) * 2 + c0;
    const char* sB0 = (const char*)W + ((size_t)(nt * 256 +       r0) * GK) * 2 + c0;
    const char* sB1 = (const char*)W + ((size_t)(nt * 256 + 128 + r0) * GK) * 2 + c0;
    char* ldsw = ldsc + wave * 1024;

    f32x4 acc[8][4];
#pragma unroll
    for (int m = 0; m < 8; ++m)
#pragma unroll
        for (int n = 0; n < 4; ++n)
            acc[m][n] = (f32x4){0.f, 0.f, 0.f, 0.f};

    short8 af[4], wf[4];

    // prologue: prefetch units 0..5 (tile0 complete + tile1 K-half0)
#pragma unroll
    for (int j = 0; j < 6; ++j)
        stage_unit(j, ldsw, sA0, sA1, sB0, sB1);
    VMCNT(8);             // units 0,1 landed (12 issued, <=8 outstanding)
    SBAR();

    for (int t = 0; t < NT12 - 2; ++t)
        TILE(t, VMCNT(8), VMCNT(8));
    TILE(10, VMCNT(8), VMCNT(4));   // tail drain begins
    TILE(11, VMCNT(0), (void)0);

    // epilogue: row = mt*256 + wm*128 + m*16 + quad*4 + r ; col = nt*256 + wn*64 + n*16 + mrow
    float* Cb = C + (size_t)(mt * 256 + wm * 128 + quad * 4) * GN
                  + nt * 256 + wn * 64 + mrow;
#pragma unroll
    for (int m = 0; m < 8; ++m)
#pragma unroll
        for (int r = 0; r < 4; ++r)
#pragma unroll
            for (int n = 0; n < 4; ++n)
                Cb[(size_t)(m * 16 + r) * GN + n * 16] = acc[m][n][r];
}

// ---------------------------------------------------------------------------
__global__ __launch_bounds__(256) void cvt_bf16_kernel(
    const float* __restrict__ in, ushort_t* __restrict__ out, int n4)
{
    int i = blockIdx.x * 256 + threadIdx.x;
    if (i >= n4) return;
    float4 v = ((const float4*)in)[i];
    ushort4 o;
    o.x = f2bf(v.x); o.y = f2bf(v.y); o.z = f2bf(v.z); o.w = f2bf(v.w);
    ((ushort4*)out)[i] = o;
}

__global__ __launch_bounds__(256) void cvt_bcw_kernel(
    const float* __restrict__ bcw, ushort_t* __restrict__ out)
{
    int i = blockIdx.x * 256 + threadIdx.x;
    if (i >= 2 * 128 * 1536 / 4) return;
    int e = i * 4;
    int layer = e / (128 * 1536);
    int rem = e % (128 * 1536);
    int row = rem / 1536, col = rem % 1536;
    ushort4 o = {0, 0, 0, 0};
    if (row < 80) {
        float4 v = *(const float4*)(bcw + ((size_t)layer * 80 + row) * 1536 + col);
        o.x = f2bf(v.x); o.y = f2bf(v.y); o.z = f2bf(v.z); o.w = f2bf(v.w);
    }
    ((ushort4*)out)[i] = o;
}

__global__ __launch_bounds__(256) void zero_kernel(float* __restrict__ p, int n)
{
    int i = blockIdx.x * 256 + threadIdx.x;
    if (i < n) p[i] = 0.f;
}

// ---------------------------------------------------------------------------
__global__ __launch_bounds__(256) void embed_kernel(
    const int* __restrict__ x, const float* __restrict__ emb, float* __restrict__ h)
{
    int idx = blockIdx.x * 256 + threadIdx.x;
    if (idx >= BT * (DD / 4)) return;
    int row = idx / (DD / 4), c = idx % (DD / 4);
    ((float4*)h)[idx] = ((const float4*)(emb + (size_t)x[row] * DD))[c];
}

__global__ __launch_bounds__(256) void rmsnorm_kernel(
    const float* __restrict__ h, const float* __restrict__ w, ushort_t* __restrict__ out)
{
    int row = blockIdx.x, tid = threadIdx.x;
    const float* hr = h + (size_t)row * DD;
    float s = 0.f;
    for (int i = tid; i < DD; i += 256) { float v = hr[i]; s += v * v; }
#pragma unroll
    for (int off = 32; off >= 1; off >>= 1) s += __shfl_xor(s, off);
    __shared__ float part[4];
    if ((tid & 63) == 0) part[tid >> 6] = s;
    __syncthreads();
    float tot = part[0] + part[1] + part[2] + part[3];
    float sc = rsqrtf(tot * (1.0f / DD) + EPS);
    for (int i = tid; i < DD; i += 256)
        out[(size_t)row * DD + i] = f2bf(hr[i] * sc * w[i]);
}

__global__ __launch_bounds__(256) void conv_silu_kernel(
    const float* __restrict__ xz, const float* __restrict__ cw,
    const float* __restrict__ cb, float* __restrict__ xi, ushort_t* __restrict__ xi16)
{
    int idx = blockIdx.x * 256 + threadIdx.x;
    if (idx >= BT * DI) return;
    int d = idx % DI, bt = idx / DI, t = bt % LL;
    const float* base = xz + (size_t)bt * (2 * DI) + d;
    float w0 = cw[d * 4 + 0], w1 = cw[d * 4 + 1], w2 = cw[d * 4 + 2], w3 = cw[d * 4 + 3];
    float acc = cb[d] + base[0] * w3;
    if (t >= 1) acc += base[-(ptrdiff_t)(2 * DI)] * w2;
    if (t >= 2) acc += base[-(ptrdiff_t)(4 * DI)] * w1;
    if (t >= 3) acc += base[-(ptrdiff_t)(6 * DI)] * w0;
    float v = acc / (1.0f + expf(-acc));
    xi[idx] = v;
    xi16[idx] = f2bf(v);
}

__global__ __launch_bounds__(256) void delta_kernel(
    const float* __restrict__ bcd, const float* __restrict__ dw,
    const float* __restrict__ db, float* __restrict__ delta)
{
    int row = blockIdx.x / 6, chunk = blockIdx.x % 6;
    int d = chunk * 256 + threadIdx.x;
    __shared__ float dlt_s[DRR];
    if (threadIdx.x < DRR) dlt_s[threadIdx.x] = bcd[(size_t)row * 80 + 32 + threadIdx.x];
    __syncthreads();
    float z = db[d];
    const float* wr = dw + (size_t)d * DRR;
#pragma unroll
    for (int r = 0; r < DRR; ++r) z = fmaf(dlt_s[r], wr[r], z);
    delta[(size_t)row * DI + d] = (z > 20.f) ? z : log1pf(expf(z));
}

// ---------------------------------------------------------------------------
// Chunked S6 scan. Pass 1: per-chunk local scan from h=0 -> (A_cum, h_end).
// Pass 2: sequential combine over chunks -> h_init. Pass 3: local scan from
// h_init, DPP row-reduction for y.
// blockIdx.x = (b*(DI/16) + dbi)*NCH + c ; thread: n=lane&15, dl=wave*4+lane>>4
// ---------------------------------------------------------------------------
__global__ __launch_bounds__(256) void scan_pass1(
    const float* __restrict__ delta, const float* __restrict__ xi,
    const float* __restrict__ bcd, const float* __restrict__ lA,
    float* __restrict__ a_cum, float* __restrict__ h_end)
{
    int blk  = blockIdx.x;
    int c    = blk % NCH;
    int rest = blk / NCH;
    int b    = rest / (DI / 16);
    int dbi  = rest % (DI / 16);
    int dblk = dbi * 16;
    int tid  = threadIdx.x, lane = tid & 63, wave = tid >> 6;
    int n = lane & 15, dl = wave * 4 + (lane >> 4), d = dblk + dl;

    float Av   = -expf(lA[(size_t)d * NS + n]);
    float A2   = Av * 1.44269504088896f;
    float invA = 1.0f / Av;

    __shared__ float2 s_dx[TC][16];
    __shared__ float  s_B [TC][16];

    const float* dbase = delta + ((size_t)b * LL + c * TC) * DI + dblk;
    const float* xbase = xi    + ((size_t)b * LL + c * TC) * DI + dblk;
    const float* bcb   = bcd   + ((size_t)b * LL + c * TC) * 80;

    for (int i = tid; i < TC * 16; i += 256) {
        int tt = i >> 4, dd = i & 15;
        s_dx[tt][dd] = make_float2(dbase[(size_t)tt * DI + dd],
                                   xbase[(size_t)tt * DI + dd]);
        s_B[tt][dd]  = bcb[(size_t)tt * 80 + dd];
    }
    __syncthreads();

    float hs = 0.f, sd = 0.f;
#pragma unroll 4
    for (int tt = 0; tt < TC; ++tt) {
        float2 dx = s_dx[tt][dl];
        float Bv  = s_B[tt][n];
        float Ab  = exp2f(dx.x * A2);
        float u   = (Ab - 1.0f) * invA * Bv * dx.y;
        hs = fmaf(Ab, hs, u);
        sd += dx.x;
    }
    size_t o = (((size_t)b * NCH + c) * (DI / 16) + dbi) * 256 + dl * 16 + n;
    a_cum[o] = exp2f(A2 * sd);
    h_end[o] = hs;
}

__global__ __launch_bounds__(256) void scan_pass2(
    const float* __restrict__ a_cum, const float* __restrict__ h_end,
    float* __restrict__ h_init)
{
    int gid = blockIdx.x * 256 + threadIdx.x;   // over BB * CHW
    if (gid >= BB * CHW) return;
    int b = gid / CHW, r = gid % CHW;
    size_t base = (size_t)b * NCH * CHW + r;
    float h = 0.f;
#pragma unroll
    for (int c = 0; c < NCH; ++c) {
        h_init[base + (size_t)c * CHW] = h;
        h = fmaf(a_cum[base + (size_t)c * CHW], h, h_end[base + (size_t)c * CHW]);
    }
}

__global__ __launch_bounds__(256) void scan_pass3(
    const float* __restrict__ delta, const float* __restrict__ xi,
    const float* __restrict__ bcd, const float* __restrict__ lA,
    const float* __restrict__ Dp, const float* __restrict__ h_init,
    float* __restrict__ y)
{
    int blk  = blockIdx.x;
    int c    = blk % NCH;
    int rest = blk / NCH;
    int b    = rest / (DI / 16);
    int dbi  = rest % (DI / 16);
    int dblk = dbi * 16;
    int tid  = threadIdx.x, lane = tid & 63, wave = tid >> 6;
    int n = lane & 15, dl = wave * 4 + (lane >> 4), d = dblk + dl;

    float Av   = -expf(lA[(size_t)d * NS + n]);
    float A2   = Av * 1.44269504088896f;
    float invA = 1.0f / Av;
    float Dpv  = Dp[d];

    __shared__ float2 s_dx[TC][16];
    __shared__ float2 s_bc[TC][16];

    const float* dbase = delta + ((size_t)b * LL + c * TC) * DI + dblk;
    const float* xbase = xi    + ((size_t)b * LL + c * TC) * DI + dblk;
    const float* bcb   = bcd   + ((size_t)b * LL + c * TC) * 80;
    float*       ybase = y     + ((size_t)b * LL + c * TC) * DI + dblk;

    for (int i = tid; i < TC * 16; i += 256) {
        int tt = i >> 4, dd = i & 15;
        s_dx[tt][dd] = make_float2(dbase[(size_t)tt * DI + dd],
                                   xbase[(size_t)tt * DI + dd]);
        s_bc[tt][dd] = make_float2(bcb[(size_t)tt * 80 + dd],
                                   bcb[(size_t)tt * 80 + 16 + dd]);
    }
    __syncthreads();

    float hs = h_init[(((size_t)b * NCH + c) * (DI / 16) + dbi) * 256 + dl * 16 + n];

#pragma unroll 4
    for (int tt = 0; tt < TC; ++tt) {
        float2 dx = s_dx[tt][dl];
        float2 bc = s_bc[tt][n];
        float Ab  = exp2f(dx.x * A2);
        float u   = (Ab - 1.0f) * invA * bc.x * dx.y;
        hs = fmaf(Ab, hs, u);
        float r = bc.y * hs;
        r = DPP_ADD(r, 0xB1);    // + lane^1 (quad_perm [1,0,3,2])
        r = DPP_ADD(r, 0x4E);    // + lane^2 (quad_perm [2,3,0,1])
        r = DPP_ADD(r, 0x141);   // + row_half_mirror (8-lane fold)
        r = DPP_ADD(r, 0x140);   // + row_mirror (16-lane fold)
        if (n == 0) ybase[(size_t)tt * DI + dl] = fmaf(dx.y, Dpv, r);
    }
}

// yg16 = bf16( y * silu(xz[:, DI:2*DI]) )
__global__ __launch_bounds__(256) void gate_kernel(
    const float* __restrict__ y, const float* __restrict__ xz, ushort_t* __restrict__ yg16)
{
    int idx = blockIdx.x * 256 + threadIdx.x;
    if (idx >= BT * DI) return;
    int d = idx % DI, bt = idx / DI;
    float r = xz[(size_t)bt * (2 * DI) + DI + d];
    yg16[idx] = f2bf(y[idx] * r / (1.0f + expf(-r)));
}

// ---------------------------------------------------------------------------
extern "C" void kernel_launch(void* const* d_in, const int* in_sizes, int n_in,
                              void* d_out, int out_size, void* d_ws, size_t ws_size,
                              hipStream_t stream)
{
    const int*   x    = (const int*)  d_in[0];
    const float* emb  = (const float*)d_in[1];
    const float* rmsw = (const float*)d_in[2];
    const float* inw  = (const float*)d_in[3];
    const float* cw   = (const float*)d_in[4];
    const float* cb   = (const float*)d_in[5];
    const float* lA   = (const float*)d_in[6];
    const float* bcw  = (const float*)d_in[7];
    const float* dw   = (const float*)d_in[8];
    const float* db   = (const float*)d_in[9];
    const float* Dp   = (const float*)d_in[10];
    const float* ow   = (const float*)d_in[11];
    const float* nfw  = (const float*)d_in[12];
    float* out = (float*)d_out;

    float* ws = (float*)d_ws;
    float* h    = ws;                          // BT*DD
    float* xz   = h    + (size_t)BT * DD;      // BT*2*DI
    float* xi   = xz   + (size_t)BT * 2 * DI;  // BT*DI
    float* bcd  = xi   + (size_t)BT * DI;      // BT*80
    float* dlt  = bcd  + (size_t)BT * 80;      // BT*DI
    float* yb   = dlt  + (size_t)BT * DI;      // BT*DI
    float* acum = yb   + (size_t)BT * DI;      // BB*NCH*DI*NS
    float* hend = acum + (size_t)BB * NCH * DI * NS;
    float* hini = hend + (size_t)BB * NCH * DI * NS;
    ushort_t* bf = (ushort_t*)(hini + (size_t)BB * NCH * DI * NS);
    ushort_t* hn_bf  = bf;                                  // BT*DD
    ushort_t* xib_bf = hn_bf  + (size_t)BT * DD;            // BT*DI
    ushort_t* yg_bf  = xib_bf + (size_t)BT * DI;            // BT*DI
    ushort_t* emb_bf = yg_bf  + (size_t)BT * DI;            // VOC*DD
    ushort_t* inw_bf = emb_bf + (size_t)VOC * DD;           // 2*2DI*DD
    ushort_t* ow_bf  = inw_bf + (size_t)2 * 2 * DI * DD;    // 2*DD*DI
    ushort_t* bcw_bf = ow_bf  + (size_t)2 * DD * DI;        // 2*128*1536

    cvt_bf16_kernel<<<(VOC * DD / 4 + 255) / 256, 256, 0, stream>>>(emb, emb_bf, VOC * DD / 4);
    cvt_bf16_kernel<<<(2 * 2 * DI * DD / 4 + 255) / 256, 256, 0, stream>>>(inw, inw_bf, 2 * 2 * DI * DD / 4);
    cvt_bf16_kernel<<<(2 * DD * DI / 4 + 255) / 256, 256, 0, stream>>>(ow, ow_bf, 2 * DD * DI / 4);
    cvt_bcw_kernel<<<(2 * 128 * 1536 / 4 + 255) / 256, 256, 0, stream>>>(bcw, bcw_bf);

    embed_kernel<<<(BT * (DD / 4) + 255) / 256, 256, 0, stream>>>(x, emb, h);

    for (int layer = 0; layer < 2; ++layer) {
        rmsnorm_kernel<<<BT, 256, 0, stream>>>(h, rmsw + (size_t)layer * DD, hn_bf);

        // xz = hn @ in_w^T : M=2048 N=3072 K=768
        gemm_bf16<false, false, false><<<dim3(BT / 128, 2 * DI / 128, 1), 256, 0, stream>>>(
            hn_bf, inw_bf + (size_t)layer * 2 * DI * DD, xz, 2 * DI, DD, 2 * DI, DD);

        conv_silu_kernel<<<(BT * DI + 255) / 256, 256, 0, stream>>>(
            xz, cw + (size_t)layer * DI * KC, cb + (size_t)layer * DI, xi, xib_bf);

        zero_kernel<<<(BT * 80 + 255) / 256, 256, 0, stream>>>(bcd, BT * 80);

        // bcd = xi @ bcw^T : M=2048 N=80(pad128) K=1536, split-K=8
        gemm_bf16<false, true, true><<<dim3(BT / 128, 1, 8), 256, 0, stream>>>(
            xib_bf, bcw_bf + (size_t)layer * 128 * 1536, bcd, 80, DI, 80, DI / 8);

        delta_kernel<<<BT * 6, 256, 0, stream>>>(
            bcd, dw + (size_t)layer * DI * DRR, db + (size_t)layer * DI, dlt);

        scan_pass1<<<BB * (DI / 16) * NCH, 256, 0, stream>>>(
            dlt, xi, bcd, lA + (size_t)layer * DI * NS, acum, hend);
        scan_pass2<<<(BB * CHW + 255) / 256, 256, 0, stream>>>(acum, hend, hini);
        scan_pass3<<<BB * (DI / 16) * NCH, 256, 0, stream>>>(
            dlt, xi, bcd, lA + (size_t)layer * DI * NS, Dp + (size_t)layer * DI, hini, yb);

        gate_kernel<<<(BT * DI + 255) / 256, 256, 0, stream>>>(yb, xz, yg_bf);

        // h += y @ ow^T : M=2048 N=768 K=1536
        gemm_bf16<true, false, false><<<dim3(BT / 128, DD / 128, 1), 256, 0, stream>>>(
            yg_bf, ow_bf + (size_t)layer * DD * DI, h, DD, DI, DD, DI);
    }

    rmsnorm_kernel<<<BT, 256, 0, stream>>>(h, nfw, hn_bf);

    // logits = hn @ emb^T : M=2048 N=32000 K=768 — 256² deep-pipelined
    gemm_logits_256<<<dim3(BT / 256 * (VOC / 256)), 512, 0, stream>>>(
        hn_bf, emb_bf, out);
}

// Round 2
// 870.227 us; speedup vs baseline: 1.0640x; 1.0117x over previous
//
#include <hip/hip_runtime.h>
#include <math.h>

#define BB 2
#define LL 1024
#define DD 768
#define DI 1536
#define NS 16
#define DRR 48
#define KC 4
#define VOC 32000
#define BT (BB*LL)          // 2048 rows
#define EPS 1e-5f

#define NCH 16              // scan chunks
#define TC  (LL/NCH)        // 64 timesteps per chunk
#define CHW ((DI/16)*256)   // elems per (b,chunk) in state bufs = 24576

typedef __attribute__((ext_vector_type(4))) float f32x4;
typedef __attribute__((ext_vector_type(8))) short short8;
typedef unsigned short ushort_t;

__device__ __forceinline__ unsigned short f2bf(float f) {
    unsigned int u = __float_as_uint(f);
    u += 0x7FFFu + ((u >> 16) & 1u);   // RNE
    return (unsigned short)(u >> 16);
}

// async global->LDS, 16B per lane; lds base must be wave-uniform, HW adds lane*16
#define GLDS(gp, lp) __builtin_amdgcn_global_load_lds( \
    (const __attribute__((address_space(1))) unsigned int*)(gp), \
    (__attribute__((address_space(3))) unsigned int*)(lp), 16, 0, 0)

// 16-lane (DPP row) sum reduction, all VALU-rate: quad_perm swaps + mirrors
#define DPP_ADD(c, ctrl) ((c) + __int_as_float(__builtin_amdgcn_update_dpp( \
    0, __float_as_int(c), (ctrl), 0xF, 0xF, true)))

// ---------------------------------------------------------------------------
// C = A(MxK,bf16) * W(NxK,bf16)^T [+C / atomic], fp32 out.
// 128x128 tile, BK=32, global_load_lds width-16 staging, T3-minimum 2-phase
// double buffer: STAGE(next) issued BEFORE ds_read+MFMA(current); single
// vmcnt(0)+barrier per K-step (the __syncthreads drain IS the recipe's wait).
// ---------------------------------------------------------------------------
template<bool ADD, bool NMASK, bool ATOMIC>
__global__ __launch_bounds__(256) void gemm_bf16(
    const ushort_t* __restrict__ A, const ushort_t* __restrict__ W,
    float* C, int Nn, int lda, int ldc, int kchunk)
{
    __shared__ __align__(16) ushort_t As[2 * 128 * 32];
    __shared__ __align__(16) ushort_t Ws[2 * 128 * 32];

    const int row0 = blockIdx.x * 128;
    const int col0 = blockIdx.y * 128;
    const int tid  = threadIdx.x;
    const int lane = tid & 63;
    const int wave = tid >> 6;
    const int wm   = (wave & 1) * 64;
    const int wn   = (wave >> 1) * 64;
    const int mrow = lane & 15;
    const int quad = lane >> 4;
    const int kb   = blockIdx.z * kchunk;

    const int srow = tid >> 2;
    const int scol = (tid & 3) << 3;
    const ushort_t* gA0 = A + (size_t)(row0 + srow) * lda + scol;
    const ushort_t* gA1 = A + (size_t)(row0 + 64 + srow) * lda + scol;
    const ushort_t* gW0 = W + (size_t)(col0 + srow) * lda + scol;
    const ushort_t* gW1 = W + (size_t)(col0 + 64 + srow) * lda + scol;

#define STAGE_MM(buf, kk) do { \
    char* a_ = (char*)As + (buf) * 8192 + wave * 1024; \
    char* w_ = (char*)Ws + (buf) * 8192 + wave * 1024; \
    GLDS(gA0 + (kk), a_); GLDS(gA1 + (kk), a_ + 4096); \
    GLDS(gW0 + (kk), w_); GLDS(gW1 + (kk), w_ + 4096); \
} while (0)

    f32x4 acc[4][4];
#pragma unroll
    for (int i = 0; i < 4; ++i)
#pragma unroll
        for (int j = 0; j < 4; ++j)
            acc[i][j] = (f32x4){0.f, 0.f, 0.f, 0.f};

    STAGE_MM(0, kb);
    __syncthreads();                 // drains vmcnt(0): buf0 landed

    int cur = 0;
    for (int k0 = kb; k0 < kb + kchunk; k0 += 32) {
        if (k0 + 32 < kb + kchunk) STAGE_MM(cur ^ 1, k0 + 32);  // overlap w/ compute

        const ushort_t* Ab = As + cur * 4096;
        const ushort_t* Wb = Ws + cur * 4096;
        short8 af[4], wf[4];
#pragma unroll
        for (int i = 0; i < 4; ++i) {
            af[i] = *(const short8*)&Ab[(wm + i * 16 + mrow) * 32 + quad * 8];
            wf[i] = *(const short8*)&Wb[(wn + i * 16 + mrow) * 32 + quad * 8];
        }
#pragma unroll
        for (int i = 0; i < 4; ++i)
#pragma unroll
            for (int j = 0; j < 4; ++j)
                acc[i][j] = __builtin_amdgcn_mfma_f32_16x16x32_bf16(
                    af[i], wf[j], acc[i][j], 0, 0, 0);
        __syncthreads();             // one vmcnt(0)+barrier per K-step (T3 recipe)
        cur ^= 1;
    }
#undef STAGE_MM

#pragma unroll
    for (int i = 0; i < 4; ++i)
#pragma unroll
        for (int j = 0; j < 4; ++j)
#pragma unroll
            for (int r = 0; r < 4; ++r) {
                int row = row0 + wm + i * 16 + quad * 4 + r;
                int col = col0 + wn + j * 16 + mrow;
                if (!NMASK || col < Nn) {
                    float v = acc[i][j][r];
                    size_t off = (size_t)row * ldc + col;
                    if (ATOMIC) {
                        atomicAdd(&C[off], v);
                    } else {
                        if (ADD) v += C[off];
                        C[off] = v;
                    }
                }
            }
}

// ---------------------------------------------------------------------------
// 256x256 deep-pipelined logits GEMM: C(2048x32000,f32) = A(2048x768) W(32000x768)^T
// T1 XCD swizzle + T2 LDS XOR swizzle + T3 phase-split + T4 counted vmcnt + T5 setprio.
// Epilogue uses NONTEMPORAL stores: the 262MB streaming fp32 C-write must not
// flush the A-tile / B-panels out of L2 between block rounds.
// ---------------------------------------------------------------------------
#define GK  768
#define GN  32000
#define NT12 12

__device__ __forceinline__ void stage_unit(
    int j, char* ldsw, const char* sA0, const char* sA1,
    const char* sB0, const char* sB1)
{
    if (j >= 4 * NT12) return;
    int tt = j >> 2, hh = (j >> 1) & 1, ee = j & 1;
    int koff = tt * 128 + hh * 64;           // bytes into the K dimension
    char* dst = ldsw + (j & 7) * 16384;
    const char* s0 = (ee ? sB0 : sA0) + koff;
    const char* s1 = (ee ? sB1 : sA1) + koff;
    GLDS(s0, dst);
    GLDS(s1, dst + 8192);
}

#define VMCNT(N) asm volatile("s_waitcnt vmcnt(" #N ")" ::: "memory")

#define SBAR() do { __builtin_amdgcn_sched_barrier(0); \
    __builtin_amdgcn_s_barrier(); \
    __builtin_amdgcn_sched_barrier(0); } while (0)

#define MFMA16(M2) do { \
    __builtin_amdgcn_s_setprio(1); \
    _Pragma("unroll") \
    for (int i_ = 0; i_ < 4; ++i_) \
        _Pragma("unroll") \
        for (int n_ = 0; n_ < 4; ++n_) \
            acc[(M2)*4 + i_][n_] = __builtin_amdgcn_mfma_f32_16x16x32_bf16( \
                af[i_], wf[n_], acc[(M2)*4 + i_][n_], 0, 0, 0); \
    __builtin_amdgcn_s_setprio(0); \
} while (0)

#define PHASE(T, H, M2, LOADB, WAITSTMT) do { \
    const char* bufA_ = ldsc + ((T) & 1) * 65536 + (H) * 32768; \
    if (LOADB) { \
        _Pragma("unroll") \
        for (int n_ = 0; n_ < 4; ++n_) \
            wf[n_] = *(const short8*)(bufA_ + 16384 + offB[n_]); \
    } \
    _Pragma("unroll") \
    for (int i_ = 0; i_ < 4; ++i_) \
        af[i_] = *(const short8*)(bufA_ + offA[(M2)*4 + i_]); \
    stage_unit(4*(T) + 2*(H) + (M2) + 6, ldsw, sA0, sA1, sB0, sB1); \
    SBAR(); \
    MFMA16(M2); \
    WAITSTMT; \
    SBAR(); \
} while (0)

#define TILE(T, W1, W2) do { \
    PHASE(T, 0, 0, true,  (void)0); \
    PHASE(T, 0, 1, false, W1); \
    PHASE(T, 1, 0, true,  (void)0); \
    PHASE(T, 1, 1, false, W2); \
} while (0)

__global__ __launch_bounds__(512, 2) void gemm_logits_256(
    const ushort_t* __restrict__ A, const ushort_t* __restrict__ W,
    float* __restrict__ C)
{
    __shared__ __align__(16) char ldsc[131072];

    // T1: bijective XCD swizzle (1000 % 8 == 0); each XCD owns contiguous
    // s-range -> all 8 m-tiles of a B-panel land on the same L2.
    const int bid = blockIdx.x;
    const int s   = (bid & 7) * 125 + (bid >> 3);
    const int mt  = s & 7;        // M tile (8)
    const int nt  = s >> 3;       // N tile (125)

    const int tid  = threadIdx.x;
    const int lane = tid & 63;
    const int wave = tid >> 6;
    const int wm   = wave >> 2;   // 0..1
    const int wn   = wave & 3;    // 0..3
    const int mrow = lane & 15;
    const int quad = lane >> 4;

    // swizzled ds_read byte offsets within a 256x32 (16KB) unit
    int offA[8], offB[4];
#pragma unroll
    for (int m = 0; m < 8; ++m) {
        int r = wm * 128 + m * 16 + mrow;
        offA[m] = r * 64 + ((quad * 16) ^ (((r >> 1) & 3) << 4));
    }
#pragma unroll
    for (int n = 0; n < 4; ++n) {
        int r = wn * 64 + n * 16 + mrow;
        offB[n] = r * 64 + ((quad * 16) ^ (((r >> 1) & 3) << 4));
    }

    // staging: thread covers LDS chunks X0=tid*16 (rows 0-127) and X0+8192
    // (rows 128-255); global source pre-swizzled with the same involution.
    const int X0 = tid * 16;
    const int L0 = X0 ^ (((X0 >> 7) & 3) << 4);
    const int r0 = L0 >> 6, c0 = L0 & 63;
    const char* sA0 = (const char*)A + ((size_t)(mt * 256 +       r0) * GK) * 2 + c0;
    const char* sA1 = (const char*)A + ((size_t)(mt * 256 + 128 + r0) * GK) * 2 + c0;
    const char* sB0 = (const char*)W + ((size_t)(nt * 256 +       r0) * GK) * 2 + c0;
    const char* sB1 = (const char*)W + ((size_t)(nt * 256 + 128 + r0) * GK) * 2 + c0;
    char* ldsw = ldsc + wave * 1024;

    f32x4 acc[8][4];
#pragma unroll
    for (int m = 0; m < 8; ++m)
#pragma unroll
        for (int n = 0; n < 4; ++n)
            acc[m][n] = (f32x4){0.f, 0.f, 0.f, 0.f};

    short8 af[4], wf[4];

    // prologue: prefetch units 0..5 (tile0 complete + tile1 K-half0)
#pragma unroll
    for (int j = 0; j < 6; ++j)
        stage_unit(j, ldsw, sA0, sA1, sB0, sB1);
    VMCNT(8);             // units 0,1 landed (12 issued, <=8 outstanding)
    SBAR();

    for (int t = 0; t < NT12 - 2; ++t)
        TILE(t, VMCNT(8), VMCNT(8));
    TILE(10, VMCNT(8), VMCNT(4));   // tail drain begins
    TILE(11, VMCNT(0), (void)0);

    // epilogue: row = mt*256 + wm*128 + m*16 + quad*4 + r ; col = nt*256 + wn*64 + n*16 + mrow
    // nontemporal: 262MB streaming write, never re-read -> keep out of L2
    float* Cb = C + (size_t)(mt * 256 + wm * 128 + quad * 4) * GN
                  + nt * 256 + wn * 64 + mrow;
#pragma unroll
    for (int m = 0; m < 8; ++m)
#pragma unroll
        for (int r = 0; r < 4; ++r)
#pragma unroll
            for (int n = 0; n < 4; ++n)
                __builtin_nontemporal_store(acc[m][n][r],
                    &Cb[(size_t)(m * 16 + r) * GN + n * 16]);
}

// ---------------------------------------------------------------------------
__global__ __launch_bounds__(256) void cvt_bf16_kernel(
    const float* __restrict__ in, ushort_t* __restrict__ out, int n4)
{
    int i = blockIdx.x * 256 + threadIdx.x;
    if (i >= n4) return;
    float4 v = ((const float4*)in)[i];
    ushort4 o;
    o.x = f2bf(v.x); o.y = f2bf(v.y); o.z = f2bf(v.z); o.w = f2bf(v.w);
    ((ushort4*)out)[i] = o;
}

__global__ __launch_bounds__(256) void cvt_bcw_kernel(
    const float* __restrict__ bcw, ushort_t* __restrict__ out)
{
    int i = blockIdx.x * 256 + threadIdx.x;
    if (i >= 2 * 128 * 1536 / 4) return;
    int e = i * 4;
    int layer = e / (128 * 1536);
    int rem = e % (128 * 1536);
    int row = rem / 1536, col = rem % 1536;
    ushort4 o = {0, 0, 0, 0};
    if (row < 80) {
        float4 v = *(const float4*)(bcw + ((size_t)layer * 80 + row) * 1536 + col);
        o.x = f2bf(v.x); o.y = f2bf(v.y); o.z = f2bf(v.z); o.w = f2bf(v.w);
    }
    ((ushort4*)out)[i] = o;
}

// ---------------------------------------------------------------------------
// embed + layer-0 rmsnorm fused: one block per row
__global__ __launch_bounds__(256) void embed_norm_kernel(
    const int* __restrict__ x, const float* __restrict__ emb,
    const float* __restrict__ w, float* __restrict__ h, ushort_t* __restrict__ out)
{
    int row = blockIdx.x, tid = threadIdx.x;
    const float* er = emb + (size_t)x[row] * DD;
    float v0 = er[tid], v1 = er[tid + 256], v2 = er[tid + 512];
    float s = v0 * v0 + v1 * v1 + v2 * v2;
#pragma unroll
    for (int off = 32; off >= 1; off >>= 1) s += __shfl_xor(s, off);
    __shared__ float part[4];
    if ((tid & 63) == 0) part[tid >> 6] = s;
    __syncthreads();
    float sc = rsqrtf((part[0] + part[1] + part[2] + part[3]) * (1.0f / DD) + EPS);
    float* hr = h + (size_t)row * DD;
    hr[tid] = v0; hr[tid + 256] = v1; hr[tid + 512] = v2;
    ushort_t* o = out + (size_t)row * DD;
    o[tid]       = f2bf(v0 * sc * w[tid]);
    o[tid + 256] = f2bf(v1 * sc * w[tid + 256]);
    o[tid + 512] = f2bf(v2 * sc * w[tid + 512]);
}

__global__ __launch_bounds__(256) void rmsnorm_kernel(
    const float* __restrict__ h, const float* __restrict__ w, ushort_t* __restrict__ out)
{
    int row = blockIdx.x, tid = threadIdx.x;
    const float* hr = h + (size_t)row * DD;
    float s = 0.f;
    for (int i = tid; i < DD; i += 256) { float v = hr[i]; s += v * v; }
#pragma unroll
    for (int off = 32; off >= 1; off >>= 1) s += __shfl_xor(s, off);
    __shared__ float part[4];
    if ((tid & 63) == 0) part[tid >> 6] = s;
    __syncthreads();
    float tot = part[0] + part[1] + part[2] + part[3];
    float sc = rsqrtf(tot * (1.0f / DD) + EPS);
    for (int i = tid; i < DD; i += 256)
        out[(size_t)row * DD + i] = f2bf(hr[i] * sc * w[i]);
}

// conv+silu; also zeroes the bcd accumulator (bcd gemm is atomic split-K)
__global__ __launch_bounds__(256) void conv_silu_kernel(
    const float* __restrict__ xz, const float* __restrict__ cw,
    const float* __restrict__ cb, float* __restrict__ xi, ushort_t* __restrict__ xi16,
    float* __restrict__ bcd)
{
    int idx = blockIdx.x * 256 + threadIdx.x;
    if (idx >= BT * DI) return;
    if (idx < BT * 80) bcd[idx] = 0.f;
    int d = idx % DI, bt = idx / DI, t = bt % LL;
    const float* base = xz + (size_t)bt * (2 * DI) + d;
    float w0 = cw[d * 4 + 0], w1 = cw[d * 4 + 1], w2 = cw[d * 4 + 2], w3 = cw[d * 4 + 3];
    float acc = cb[d] + base[0] * w3;
    if (t >= 1) acc += base[-(ptrdiff_t)(2 * DI)] * w2;
    if (t >= 2) acc += base[-(ptrdiff_t)(4 * DI)] * w1;
    if (t >= 3) acc += base[-(ptrdiff_t)(6 * DI)] * w0;
    float v = acc / (1.0f + expf(-acc));
    xi[idx] = v;
    xi16[idx] = f2bf(v);
}

__global__ __launch_bounds__(256) void delta_kernel(
    const float* __restrict__ bcd, const float* __restrict__ dw,
    const float* __restrict__ db, float* __restrict__ delta)
{
    int row = blockIdx.x / 6, chunk = blockIdx.x % 6;
    int d = chunk * 256 + threadIdx.x;
    __shared__ float dlt_s[DRR];
    if (threadIdx.x < DRR) dlt_s[threadIdx.x] = bcd[(size_t)row * 80 + 32 + threadIdx.x];
    __syncthreads();
    float z = db[d];
    const float* wr = dw + (size_t)d * DRR;
#pragma unroll
    for (int r = 0; r < DRR; ++r) z = fmaf(dlt_s[r], wr[r], z);
    delta[(size_t)row * DI + d] = (z > 20.f) ? z : log1pf(expf(z));
}

// ---------------------------------------------------------------------------
// Chunked S6 scan. Pass 1: per-chunk local scan from h=0 -> (A_cum, h_end).
// Pass 2: sequential combine over chunks -> h_init. Pass 3: local scan from
// h_init, DPP row-reduction for y, FUSED with the silu gate -> writes yg bf16.
// blockIdx.x = (b*(DI/16) + dbi)*NCH + c ; thread: n=lane&15, dl=wave*4+lane>>4
// ---------------------------------------------------------------------------
__global__ __launch_bounds__(256) void scan_pass1(
    const float* __restrict__ delta, const float* __restrict__ xi,
    const float* __restrict__ bcd, const float* __restrict__ lA,
    float* __restrict__ a_cum, float* __restrict__ h_end)
{
    int blk  = blockIdx.x;
    int c    = blk % NCH;
    int rest = blk / NCH;
    int b    = rest / (DI / 16);
    int dbi  = rest % (DI / 16);
    int dblk = dbi * 16;
    int tid  = threadIdx.x, lane = tid & 63, wave = tid >> 6;
    int n = lane & 15, dl = wave * 4 + (lane >> 4), d = dblk + dl;

    float Av   = -expf(lA[(size_t)d * NS + n]);
    float A2   = Av * 1.44269504088896f;
    float invA = 1.0f / Av;

    __shared__ float2 s_dx[TC][16];
    __shared__ float  s_B [TC][16];

    const float* dbase = delta + ((size_t)b * LL + c * TC) * DI + dblk;
    const float* xbase = xi    + ((size_t)b * LL + c * TC) * DI + dblk;
    const float* bcb   = bcd   + ((size_t)b * LL + c * TC) * 80;

    for (int i = tid; i < TC * 16; i += 256) {
        int tt = i >> 4, dd = i & 15;
        s_dx[tt][dd] = make_float2(dbase[(size_t)tt * DI + dd],
                                   xbase[(size_t)tt * DI + dd]);
        s_B[tt][dd]  = bcb[(size_t)tt * 80 + dd];
    }
    __syncthreads();

    float hs = 0.f, sd = 0.f;
#pragma unroll 4
    for (int tt = 0; tt < TC; ++tt) {
        float2 dx = s_dx[tt][dl];
        float Bv  = s_B[tt][n];
        float Ab  = exp2f(dx.x * A2);
        float u   = (Ab - 1.0f) * invA * Bv * dx.y;
        hs = fmaf(Ab, hs, u);
        sd += dx.x;
    }
    size_t o = (((size_t)b * NCH + c) * (DI / 16) + dbi) * 256 + dl * 16 + n;
    a_cum[o] = exp2f(A2 * sd);
    h_end[o] = hs;
}

__global__ __launch_bounds__(256) void scan_pass2(
    const float* __restrict__ a_cum, const float* __restrict__ h_end,
    float* __restrict__ h_init)
{
    int gid = blockIdx.x * 256 + threadIdx.x;   // over BB * CHW
    if (gid >= BB * CHW) return;
    int b = gid / CHW, r = gid % CHW;
    size_t base = (size_t)b * NCH * CHW + r;
    float h = 0.f;
#pragma unroll
    for (int c = 0; c < NCH; ++c) {
        h_init[base + (size_t)c * CHW] = h;
        h = fmaf(a_cum[base + (size_t)c * CHW], h, h_end[base + (size_t)c * CHW]);
    }
}

__global__ __launch_bounds__(256) void scan_pass3(
    const float* __restrict__ delta, const float* __restrict__ xi,
    const float* __restrict__ bcd, const float* __restrict__ lA,
    const float* __restrict__ Dp, const float* __restrict__ h_init,
    const float* __restrict__ xz, ushort_t* __restrict__ yg)
{
    int blk  = blockIdx.x;
    int c    = blk % NCH;
    int rest = blk / NCH;
    int b    = rest / (DI / 16);
    int dbi  = rest % (DI / 16);
    int dblk = dbi * 16;
    int tid  = threadIdx.x, lane = tid & 63, wave = tid >> 6;
    int n = lane & 15, dl = wave * 4 + (lane >> 4), d = dblk + dl;

    float Av   = -expf(lA[(size_t)d * NS + n]);
    float A2   = Av * 1.44269504088896f;
    float invA = 1.0f / Av;
    float Dpv  = Dp[d];

    __shared__ float2 s_dx[TC][16];
    __shared__ float2 s_bc[TC][16];
    __shared__ float  s_rs[TC][16];   // gate input res = xz[:, DI+d]

    const float* dbase = delta + ((size_t)b * LL + c * TC) * DI + dblk;
    const float* xbase = xi    + ((size_t)b * LL + c * TC) * DI + dblk;
    const float* bcb   = bcd   + ((size_t)b * LL + c * TC) * 80;
    const float* rbase = xz    + ((size_t)b * LL + c * TC) * (2 * DI) + DI + dblk;
    ushort_t*    ygb   = yg    + ((size_t)b * LL + c * TC) * DI + dblk;

    for (int i = tid; i < TC * 16; i += 256) {
        int tt = i >> 4, dd = i & 15;
        s_dx[tt][dd] = make_float2(dbase[(size_t)tt * DI + dd],
                                   xbase[(size_t)tt * DI + dd]);
        s_bc[tt][dd] = make_float2(bcb[(size_t)tt * 80 + dd],
                                   bcb[(size_t)tt * 80 + 16 + dd]);
        s_rs[tt][dd] = rbase[(size_t)tt * (2 * DI) + dd];
    }
    __syncthreads();

    float hs = h_init[(((size_t)b * NCH + c) * (DI / 16) + dbi) * 256 + dl * 16 + n];

#pragma unroll 4
    for (int tt = 0; tt < TC; ++tt) {
        float2 dx = s_dx[tt][dl];
        float2 bc = s_bc[tt][n];
        float Ab  = exp2f(dx.x * A2);
        float u   = (Ab - 1.0f) * invA * bc.x * dx.y;
        hs = fmaf(Ab, hs, u);
        float r = bc.y * hs;
        r = DPP_ADD(r, 0xB1);    // + lane^1 (quad_perm [1,0,3,2])
        r = DPP_ADD(r, 0x4E);    // + lane^2 (quad_perm [2,3,0,1])
        r = DPP_ADD(r, 0x141);   // + row_half_mirror (8-lane fold)
        r = DPP_ADD(r, 0x140);   // + row_mirror (16-lane fold)
        if (n == 0) {
            float res = s_rs[tt][dl];
            float yv  = fmaf(dx.y, Dpv, r);
            ygb[(size_t)tt * DI + dl] = f2bf(yv * res / (1.0f + expf(-res)));
        }
    }
}

// ---------------------------------------------------------------------------
extern "C" void kernel_launch(void* const* d_in, const int* in_sizes, int n_in,
                              void* d_out, int out_size, void* d_ws, size_t ws_size,
                              hipStream_t stream)
{
    const int*   x    = (const int*)  d_in[0];
    const float* emb  = (const float*)d_in[1];
    const float* rmsw = (const float*)d_in[2];
    const float* inw  = (const float*)d_in[3];
    const float* cw   = (const float*)d_in[4];
    const float* cb   = (const float*)d_in[5];
    const float* lA   = (const float*)d_in[6];
    const float* bcw  = (const float*)d_in[7];
    const float* dw   = (const float*)d_in[8];
    const float* db   = (const float*)d_in[9];
    const float* Dp   = (const float*)d_in[10];
    const float* ow   = (const float*)d_in[11];
    const float* nfw  = (const float*)d_in[12];
    float* out = (float*)d_out;

    float* ws = (float*)d_ws;
    float* h    = ws;                          // BT*DD
    float* xz   = h    + (size_t)BT * DD;      // BT*2*DI
    float* xi   = xz   + (size_t)BT * 2 * DI;  // BT*DI
    float* bcd  = xi   + (size_t)BT * DI;      // BT*80
    float* dlt  = bcd  + (size_t)BT * 80;      // BT*DI
    float* acum = dlt  + (size_t)BT * DI;      // BB*NCH*DI*NS
    float* hend = acum + (size_t)BB * NCH * DI * NS;
    float* hini = hend + (size_t)BB * NCH * DI * NS;
    ushort_t* bf = (ushort_t*)(hini + (size_t)BB * NCH * DI * NS);
    ushort_t* hn_bf  = bf;                                  // BT*DD
    ushort_t* xib_bf = hn_bf  + (size_t)BT * DD;            // BT*DI
    ushort_t* yg_bf  = xib_bf + (size_t)BT * DI;            // BT*DI
    ushort_t* emb_bf = yg_bf  + (size_t)BT * DI;            // VOC*DD
    ushort_t* inw_bf = emb_bf + (size_t)VOC * DD;           // 2*2DI*DD
    ushort_t* ow_bf  = inw_bf + (size_t)2 * 2 * DI * DD;    // 2*DD*DI
    ushort_t* bcw_bf = ow_bf  + (size_t)2 * DD * DI;        // 2*128*1536

    cvt_bf16_kernel<<<(VOC * DD / 4 + 255) / 256, 256, 0, stream>>>(emb, emb_bf, VOC * DD / 4);
    cvt_bf16_kernel<<<(2 * 2 * DI * DD / 4 + 255) / 256, 256, 0, stream>>>(inw, inw_bf, 2 * 2 * DI * DD / 4);
    cvt_bf16_kernel<<<(2 * DD * DI / 4 + 255) / 256, 256, 0, stream>>>(ow, ow_bf, 2 * DD * DI / 4);
    cvt_bcw_kernel<<<(2 * 128 * 1536 / 4 + 255) / 256, 256, 0, stream>>>(bcw, bcw_bf);

    // embed + layer-0 rmsnorm fused
    embed_norm_kernel<<<BT, 256, 0, stream>>>(x, emb, rmsw, h, hn_bf);

    for (int layer = 0; layer < 2; ++layer) {
        if (layer)
            rmsnorm_kernel<<<BT, 256, 0, stream>>>(h, rmsw + (size_t)layer * DD, hn_bf);

        // xz = hn @ in_w^T : M=2048 N=3072 K=768
        gemm_bf16<false, false, false><<<dim3(BT / 128, 2 * DI / 128, 1), 256, 0, stream>>>(
            hn_bf, inw_bf + (size_t)layer * 2 * DI * DD, xz, 2 * DI, DD, 2 * DI, DD);

        conv_silu_kernel<<<(BT * DI + 255) / 256, 256, 0, stream>>>(
            xz, cw + (size_t)layer * DI * KC, cb + (size_t)layer * DI, xi, xib_bf, bcd);

        // bcd = xi @ bcw^T : M=2048 N=80(pad128) K=1536, split-K=8
        gemm_bf16<false, true, true><<<dim3(BT / 128, 1, 8), 256, 0, stream>>>(
            xib_bf, bcw_bf + (size_t)layer * 128 * 1536, bcd, 80, DI, 80, DI / 8);

        delta_kernel<<<BT * 6, 256, 0, stream>>>(
            bcd, dw + (size_t)layer * DI * DRR, db + (size_t)layer * DI, dlt);

        scan_pass1<<<BB * (DI / 16) * NCH, 256, 0, stream>>>(
            dlt, xi, bcd, lA + (size_t)layer * DI * NS, acum, hend);
        scan_pass2<<<(BB * CHW + 255) / 256, 256, 0, stream>>>(acum, hend, hini);
        // pass3 fused with the silu gate -> writes yg_bf directly
        scan_pass3<<<BB * (DI / 16) * NCH, 256, 0, stream>>>(
            dlt, xi, bcd, lA + (size_t)layer * DI * NS, Dp + (size_t)layer * DI, hini,
            xz, yg_bf);

        // h += y @ ow^T : M=2048 N=768 K=1536, split-K=4 (h holds residual;
        // atomicAdd partials -> 384 wgs instead of 96)
        gemm_bf16<false, false, true><<<dim3(BT / 128, DD / 128, 4), 256, 0, stream>>>(
            yg_bf, ow_bf + (size_t)layer * DD * DI, h, DD, DI, DD, DI / 4);
    }

    rmsnorm_kernel<<<BT, 256, 0, stream>>>(h, nfw, hn_bf);

    // logits = hn @ emb^T : M=2048 N=32000 K=768 — 256² deep-pipelined, nt stores
    gemm_logits_256<<<dim3(BT / 256 * (VOC / 256)), 512, 0, stream>>>(
        hn_bf, emb_bf, out);
}